// Round 3
// baseline (301.129 us; speedup 1.0000x reference)
//
#include <hip/hip_runtime.h>

// Problem: latent (16,192,64,64) fp32, codebook (1024,192) fp32.
// N = 65536 points, D = 192, K = 1024.
// d_out = [quantized: 12582912 fp32][indices-as-float: 65536].

#define NPTS   65536
#define DIMS   192
#define KCB    1024
#define HW     4096
#define QELEMS 12582912

typedef __attribute__((ext_vector_type(8))) _Float16 f16x8;
typedef __attribute__((ext_vector_type(4))) float f32x4;

// ============================ f16 MFMA path =============================
// Codebook rows are unit-normalized -> argmin dist == argmax dot, and since
// inv_norm(x) > 0 is per-point, argmax(inv*dot) == argmax(dot): rank RAW dots.
// q = trunc(fma(dot_raw, 2^16, 2^21)). If the true fp32 winner differs from
// the f16 pick, q_b - q_s <= 128*||x|| + 2 (4u dot error + c2 jitter + trunc),
// so flagging (q_b - q_s) < 152*||x|| + 4 guarantees rescore repairs it.
// Flagged points get exact fp32 batched rescore.

__device__ __forceinline__ void async_load16(const void* g, void* l) {
    __builtin_amdgcn_global_load_lds(
        (const __attribute__((address_space(1))) unsigned int*)g,
        (__attribute__((address_space(3))) unsigned int*)l, 16, 0, 0);
}

// running top-2 under MAX: b >= s; merge sorted pair (ob >= os).
__device__ __forceinline__ void top2_merge_max(unsigned& b, unsigned& s,
                                               unsigned ob, unsigned os) {
    unsigned nb = max(b, ob);
    unsigned ns = max(min(b, ob), max(s, os));
    b = nb; s = ns;
}

// ---- codebook -> f16, chunk-major [c][k][32] (chunk c = dims c*32..c*32+31) ----
__global__ __launch_bounds__(256) void k_prep_cb16(const float* __restrict__ cbk,
                                                   _Float16* __restrict__ Bpf) {
    int id = blockIdx.x * 256 + threadIdx.x;    // 196608
    if (id >= KCB * DIMS) return;
    int k = id / DIMS, d = id % DIMS;
    Bpf[((size_t)(d >> 5) * KCB + k) * 32 + (d & 31)] = (_Float16)cbk[id];
}

// ---- codebook row squared norms (rescore only) ----
__global__ __launch_bounds__(256) void k_c2(const float* __restrict__ cbk,
                                            float* __restrict__ c2) {
    int k = blockIdx.x * 256 + threadIdx.x;
    if (k >= KCB) return;
    const float4* row = (const float4*)(cbk + (size_t)k * DIMS);
    float s = 0.f;
    #pragma unroll
    for (int i = 0; i < DIMS / 4; ++i) {
        float4 v = row[i];
        s += v.x * v.x + v.y * v.y + v.z * v.z + v.w * v.w;
    }
    c2[k] = s;
}

// ---- transpose codebook fp32: cbkT[d][k] (for coalesced rescore) ----
__global__ __launch_bounds__(256) void k_cbT(const float* __restrict__ cbk,
                                             float* __restrict__ cbkT) {
    __shared__ float q[64 * 193];
    const int tid = threadIdx.x;
    const int k0 = blockIdx.x * 64;
    const int lane = tid & 63;
    const int grp = tid >> 6;
    for (int r = grp; r < 64; r += 4) {
        const float* row = cbk + (size_t)(k0 + r) * DIMS;
        for (int c = lane; c < DIMS; c += 64) q[r * 193 + c] = row[c];
    }
    __syncthreads();
    for (int d = grp; d < DIMS; d += 4) {
        cbkT[(size_t)d * KCB + k0 + lane] = q[lane * 193 + d];
    }
}

// ---- fused: direct global->reg A frags + 2-phase dbuf MFMA + argmax +
//      gather ----
// grid 512 x 256 thr (4 waves); wave w owns 32 points; each wave covers all
// 1024 codewords. A fragments af[6][2] (48 VGPR) built straight from global
// (coalesced 16-lane rows). B: 48 phases (16 strips x 3 dim-tiles of 64),
// 8 KB/tile via global_load_lds into a 2-deep dbuf; per phase:
// {stage next -> ds_read+16 MFMA current -> vmcnt(0) -> __syncthreads}.
// vmcnt(0)+syncthreads is spill-proof and fence-correct (round-2 lesson).
// XOR-swizzled B layout: unit j of codeword k holds dims (j ^ ((k>>2)&3))*8.
__global__ __launch_bounds__(256, 3) void k_gemm_f(const float* __restrict__ latent,
                                                   const _Float16* __restrict__ Bpf,
                                                   const float* __restrict__ cbk,
                                                   float* __restrict__ out_q,
                                                   float* __restrict__ idxf,
                                                   int* __restrict__ list,
                                                   int* __restrict__ cnt) {
    __shared__ __align__(16) _Float16 Bs[2][4096];   // 16 KB dbuf (64k x 64d)
    __shared__ int sidx[128];

    const int tid = threadIdx.x;
    const int wave = tid >> 6;
    const int lane = tid & 63;
    const int quad = lane >> 4;
    const int l15 = lane & 15;
    const int n0 = blockIdx.x * 128;
    const int bB = n0 >> 12;
    const int hw0 = (n0 & 4095) + wave * 32;
    const size_t latb = (size_t)bB * DIMS * HW;

    // staging constants: thread stages 16B-units {tid, tid+256} of 512
    const int su0 = tid, su1 = tid + 256;
    const int sk0 = (su0 >> 2) & 63, sk1 = (su1 >> 2) & 63;
    const int sj0 = (su0 & 3) ^ ((sk0 >> 2) & 3);
    const int sj1 = (su1 & 3) ^ ((sk1 >> 2) & 3);
    const int sc0 = su0 >> 8, sc1 = su1 >> 8;        // 0/1: 32-dim half

    // prologue: stage tile (ss=0,cj=0) into buf 0
    async_load16(Bpf + ((size_t)(0 * 2 + sc0) * KCB + 0 * 64 + sk0) * 32 + sj0 * 8,
                 &Bs[0][(size_t)su0 * 8]);
    async_load16(Bpf + ((size_t)(0 * 2 + sc1) * KCB + 0 * 64 + sk1) * 32 + sj1 * 8,
                 &Bs[0][(size_t)su1 * 8]);

    // ---- A fragments + per-point norms (no LDS round-trip) ----
    // af[c][mt]: point hw0+mt*16+l15, dims c*32+quad*8 .. +7
    f16x8 af[6][2];
    float nrm[2];
    {
        float ssq0 = 0.f, ssq1 = 0.f;
        #pragma unroll
        for (int c = 0; c < 6; ++c) {
            #pragma unroll
            for (int mt = 0; mt < 2; ++mt) {
                const float* lp = latent + latb + (size_t)(c * 32 + quad * 8) * HW
                                  + hw0 + mt * 16 + l15;
                float v[8];
                #pragma unroll
                for (int j = 0; j < 8; ++j) v[j] = lp[(size_t)j * HW];
                float s = 0.f;
                #pragma unroll
                for (int j = 0; j < 8; ++j) s = fmaf(v[j], v[j], s);
                if (mt == 0) ssq0 += s; else ssq1 += s;
                f16x8 h;
                #pragma unroll
                for (int j = 0; j < 8; ++j) h[j] = (_Float16)v[j];
                af[c][mt] = h;
            }
        }
        // sum across the 4 quad-lanes holding the same point (xor bits 4,5)
        ssq0 += __shfl_xor(ssq0, 16, 64); ssq0 += __shfl_xor(ssq0, 32, 64);
        ssq1 += __shfl_xor(ssq1, 16, 64); ssq1 += __shfl_xor(ssq1, 32, 64);
        nrm[0] = sqrtf(ssq0); nrm[1] = sqrtf(ssq1);
    }

    // swizzled B read offset (f16 elems): codeword n=nt*16+l15, unit quad^((n>>2)&3)
    const int xq = (quad ^ ((l15 >> 2) & 3)) * 8;

    unsigned rb[8], rs[8];
    #pragma unroll
    for (int i = 0; i < 8; ++i) { rb[i] = 0u; rs[i] = 0u; }

    asm volatile("s_waitcnt vmcnt(0)" ::: "memory");  // tile 0 landed
    __syncthreads();

    int cj_s = 1, ss_s = 0;                 // next tile to stage (tile 1)

    // ---- K-loop: 16 strips (64 k) x 3 dim-tiles (64 dims) = 48 phases ----
    for (int ss = 0; ss < 16; ++ss) {
        f32x4 acc[2][4];
        #pragma unroll
        for (int cj = 0; cj < 3; ++cj) {
            const int ph = ss * 3 + cj;
            // stage tile ph+1 into the other buffer (overlaps with compute)
            if (ph < 47) {
                const size_t tb = ((size_t)cj_s * 2) * KCB + (size_t)ss_s * 64;
                async_load16(Bpf + (tb + (size_t)sc0 * KCB + sk0) * 32 + sj0 * 8,
                             &Bs[(ph + 1) & 1][(size_t)su0 * 8]);
                async_load16(Bpf + (tb + (size_t)sc1 * KCB + sk1) * 32 + sj1 * 8,
                             &Bs[(ph + 1) & 1][(size_t)su1 * 8]);
                if (++cj_s == 3) { cj_s = 0; ++ss_s; }
            }
            // compute tile ph from buf[ph&1]
            const _Float16* bp = &Bs[ph & 1][0];
            f16x8 bf[8];
            #pragma unroll
            for (int h = 0; h < 2; ++h)
                #pragma unroll
                for (int nt = 0; nt < 4; ++nt)
                    bf[h * 4 + nt] =
                        *(const f16x8*)(bp + h * 2048 + (nt * 16 + l15) * 32 + xq);
            if (cj == 0) {
                #pragma unroll
                for (int mt = 0; mt < 2; ++mt)
                    #pragma unroll
                    for (int nt = 0; nt < 4; ++nt)
                        acc[mt][nt] = __builtin_amdgcn_mfma_f32_16x16x32_f16(
                            af[0][mt], bf[nt], (f32x4){0.f, 0.f, 0.f, 0.f}, 0, 0, 0);
            } else {
                #pragma unroll
                for (int mt = 0; mt < 2; ++mt)
                    #pragma unroll
                    for (int nt = 0; nt < 4; ++nt)
                        acc[mt][nt] = __builtin_amdgcn_mfma_f32_16x16x32_f16(
                            af[cj * 2][mt], bf[nt], acc[mt][nt], 0, 0, 0);
            }
            #pragma unroll
            for (int mt = 0; mt < 2; ++mt)
                #pragma unroll
                for (int nt = 0; nt < 4; ++nt)
                    acc[mt][nt] = __builtin_amdgcn_mfma_f32_16x16x32_f16(
                        af[cj * 2 + 1][mt], bf[4 + nt], acc[mt][nt], 0, 0, 0);
            // staged tile landed + all waves done reading current tile
            asm volatile("s_waitcnt vmcnt(0)" ::: "memory");
            __syncthreads();
        }
        // strip epilogue: quantize raw dots (fixed scale), top-2 merge
        const int kb = ss * 64 + l15;
        #pragma unroll
        for (int mt = 0; mt < 2; ++mt) {
            #pragma unroll
            for (int r = 0; r < 4; ++r) {
                unsigned p0 = ((unsigned)fmaf(acc[mt][0][r], 65536.f, 2097152.f) << 10) | (unsigned)(kb);
                unsigned p1 = ((unsigned)fmaf(acc[mt][1][r], 65536.f, 2097152.f) << 10) | (unsigned)(kb + 16);
                unsigned p2 = ((unsigned)fmaf(acc[mt][2][r], 65536.f, 2097152.f) << 10) | (unsigned)(kb + 32);
                unsigned p3 = ((unsigned)fmaf(acc[mt][3][r], 65536.f, 2097152.f) << 10) | (unsigned)(kb + 48);
                unsigned b01 = max(p0, p1), s01 = min(p0, p1);
                unsigned b23 = max(p2, p3), s23 = min(p2, p3);
                unsigned bb = max(b01, b23);
                unsigned s4 = max(min(b01, b23), max(s01, s23));
                top2_merge_max(rb[mt * 4 + r], rs[mt * 4 + r], bb, s4);
            }
        }
    }

    // ---- cross-l15 merge + per-point finalize (wave-local) ----
    const int pw = wave * 32;
    #pragma unroll
    for (int i = 0; i < 8; ++i) {
        unsigned b = rb[i], s = rs[i];
        #pragma unroll
        for (int off = 1; off < 16; off <<= 1) {
            unsigned ob = __shfl_xor(b, off, 64);
            unsigned os = __shfl_xor(s, off, 64);
            top2_merge_max(b, s, ob, os);
        }
        const int mt = i >> 2, r = i & 3;
        // norm of point row quad*4+r lives at lane quad*16 + quad*4 + r
        float nv = __shfl(nrm[mt], (lane & 48) + ((lane >> 4) << 2) + r, 64);
        if (l15 == 0) {
            int ploc = pw + mt * 16 + ((lane >> 4) << 2) + r;
            int k = (int)(b & 1023u);
            sidx[ploc] = k;
            idxf[n0 + ploc] = (float)k;
            unsigned Mq = (unsigned)fmaf(152.0f, nv, 4.0f);
            if (((b >> 10) - (s >> 10)) < Mq) {
                int pos = atomicAdd(cnt, 1);
                list[pos] = n0 + ploc;
            }
        }
    }

    __syncthreads();                        // sidx visible; LDS reads done

    // ---- gather epilogue (q overlays Bs: 16*193*4 = 12352 <= 16384) ----
    float* q = (float*)&Bs[0][0];
    for (int chk = 0; chk < 8; ++chk) {
        int p0c = chk * 16;
        for (int r = wave; r < 16; r += 4) {
            const float* row = cbk + (size_t)sidx[p0c + r] * DIMS;
            for (int c = lane; c < DIMS; c += 64) q[r * 193 + c] = row[c];
        }
        __syncthreads();
        float* ob = out_q + latb + (n0 & 4095) + p0c;
        #pragma unroll
        for (int i = 0; i < 12; ++i) {
            int u = i * 256 + tid;
            int c = u >> 4, p = u & 15;
            ob[(size_t)c * HW + p] = q[p * 193 + c];
        }
        __syncthreads();
    }
}

// ---- batched exact fp32 rescore: 16 flagged points per block ----
__global__ __launch_bounds__(256) void k_rescore16(const float* __restrict__ latent,
                                                   const float* __restrict__ cbkT,
                                                   const float* __restrict__ cbk,
                                                   const float* __restrict__ c2,
                                                   const int* __restrict__ list,
                                                   const int* __restrict__ cnt,
                                                   float* __restrict__ out_q,
                                                   float* __restrict__ idxf) {
    __shared__ float xs[16][200];
    __shared__ float part[16][16];
    __shared__ float inv_s[16];
    __shared__ unsigned long long best[16];
    const int tid = threadIdx.x;
    const int count = *cnt;
    const float4* ct = (const float4*)cbkT;     // [d][256] float4
    const int j = tid >> 4, dl = tid & 15;

    for (int base = blockIdx.x * 16; base < count; base += gridDim.x * 16) {
        __syncthreads();                        // guard xs/best reuse
        float ss = 0.f;
        int n = 0, bb = 0, hw = 0;
        bool valid = (base + j) < count;
        if (valid) {
            n = list[base + j]; bb = n >> 12; hw = n & 4095;
            #pragma unroll
            for (int i = 0; i < 12; ++i) {
                int d = dl + i * 16;
                float v = latent[((size_t)bb * DIMS + d) * HW + hw];
                xs[j][d] = v;
                ss = fmaf(v, v, ss);
            }
        }
        part[j][dl] = ss;
        if (tid < 16) best[tid] = ~0ull;
        __syncthreads();
        if (tid < 16) {
            float s = 0.f;
            #pragma unroll
            for (int i = 0; i < 16; ++i) s += part[tid][i];
            inv_s[tid] = 1.0f / (sqrtf(s) + 1e-8f);
        }
        __syncthreads();

        // dots: thread owns codewords 4*tid..4*tid+3 for all 16 points
        float4 a[16];
        #pragma unroll
        for (int p = 0; p < 16; ++p) a[p] = make_float4(0.f, 0.f, 0.f, 0.f);
        for (int d = 0; d < DIMS; d += 4) {
            float4 cv0 = ct[(size_t)(d + 0) * 256 + tid];
            float4 cv1 = ct[(size_t)(d + 1) * 256 + tid];
            float4 cv2 = ct[(size_t)(d + 2) * 256 + tid];
            float4 cv3 = ct[(size_t)(d + 3) * 256 + tid];
            #pragma unroll
            for (int p = 0; p < 16; ++p) {
                float4 xv = *(const float4*)&xs[p][d];
                a[p].x = fmaf(xv.x, cv0.x, a[p].x); a[p].y = fmaf(xv.x, cv0.y, a[p].y);
                a[p].z = fmaf(xv.x, cv0.z, a[p].z); a[p].w = fmaf(xv.x, cv0.w, a[p].w);
                a[p].x = fmaf(xv.y, cv1.x, a[p].x); a[p].y = fmaf(xv.y, cv1.y, a[p].y);
                a[p].z = fmaf(xv.y, cv1.z, a[p].z); a[p].w = fmaf(xv.y, cv1.w, a[p].w);
                a[p].x = fmaf(xv.z, cv2.x, a[p].x); a[p].y = fmaf(xv.z, cv2.y, a[p].y);
                a[p].z = fmaf(xv.z, cv2.z, a[p].z); a[p].w = fmaf(xv.z, cv2.w, a[p].w);
                a[p].x = fmaf(xv.w, cv3.x, a[p].x); a[p].y = fmaf(xv.w, cv3.y, a[p].y);
                a[p].z = fmaf(xv.w, cv3.z, a[p].z); a[p].w = fmaf(xv.w, cv3.w, a[p].w);
            }
        }
        #pragma unroll
        for (int p = 0; p < 16; ++p) {
            float inv = inv_s[p];
            float dot4[4] = {a[p].x, a[p].y, a[p].z, a[p].w};
            unsigned long long loc = ~0ull;
            #pragma unroll
            for (int e = 0; e < 4; ++e) {
                int k = 4 * tid + e;
                float dist = c2[k] - 2.f * inv * dot4[e];
                unsigned ub = __float_as_uint(dist);
                ub ^= (ub >> 31) ? 0xFFFFFFFFu : 0x80000000u;   // monotonic
                unsigned long long pk =
                    ((unsigned long long)ub << 32) | (unsigned)k;
                loc = loc < pk ? loc : pk;
            }
            #pragma unroll
            for (int off = 1; off < 64; off <<= 1) {
                unsigned long long o = __shfl_xor(loc, off, 64);
                loc = loc < o ? loc : o;
            }
            if ((tid & 63) == 0) atomicMin(&best[p], loc);
        }
        __syncthreads();
        if (valid) {
            int kk = (int)(best[j] & 0xFFFFFFFFull);
            #pragma unroll
            for (int i = 0; i < 12; ++i) {
                int d = dl + i * 16;
                out_q[((size_t)bb * DIMS + d) * HW + hw] = cbk[(size_t)kk * DIMS + d];
            }
            if (dl == 0) idxf[n] = (float)kk;
        }
    }
}

// ======================= fallback fp32 path (round-1) ====================
__global__ __launch_bounds__(256) void k_norms_fb(const float* __restrict__ latent,
                                                  float* __restrict__ inv_norm) {
    __shared__ float red[256];
    const int tid = threadIdx.x;
    const int n0 = blockIdx.x * 128;
    const int nl = tid & 127;
    const int half = tid >> 7;
    const int b = n0 >> 12;
    const int hw = (n0 & 4095) + nl;
    const float* base = latent + (size_t)b * DIMS * HW + hw;
    float ssq = 0.f;
    for (int c = half; c < DIMS; c += 2) {
        float v = base[(size_t)c * HW];
        ssq = fmaf(v, v, ssq);
    }
    red[tid] = ssq;
    __syncthreads();
    if (half == 0) {
        float s = red[tid] + red[tid + 128];
        inv_norm[n0 + nl] = 1.0f / (sqrtf(s) + 1e-8f);
    }
}

#define LDX  132
__global__ __launch_bounds__(256) void k_dist_fb(const float* __restrict__ latent,
                                                 const float* __restrict__ cbk,
                                                 const float* __restrict__ inv_norm,
                                                 const float* __restrict__ c2,
                                                 int* __restrict__ idx_out,
                                                 float* __restrict__ idxf_out) {
    __shared__ __align__(16) float xsm[64 * LDX];
    __shared__ __align__(16) float csm[64 * LDX];
    __shared__ unsigned long long red[128];
    const int tid = threadIdx.x;
    const int n0 = blockIdx.x * 128;
    const int b = n0 >> 12;
    const int hw0 = n0 & 4095;
    const int kt = tid & 15;
    const int mt = tid >> 4;
    const float* lat_base = latent + (size_t)b * DIMS * HW + hw0;
    float inv[8];
    #pragma unroll
    for (int i = 0; i < 8; ++i) inv[i] = inv_norm[n0 + mt * 8 + i];
    float best[8];
    int bidx[8];
    #pragma unroll
    for (int i = 0; i < 8; ++i) { best[i] = 3.4e38f; bidx[i] = 0; }
    const int nl = tid & 127;
    const int cp = tid >> 7;
    for (int k0 = 0; k0 < KCB; k0 += 128) {
        float acc[8][8];
        #pragma unroll
        for (int i = 0; i < 8; ++i)
            #pragma unroll
            for (int j = 0; j < 8; ++j) acc[i][j] = 0.f;
        for (int d0 = 0; d0 < DIMS; d0 += 64) {
            __syncthreads();
            for (int cc = cp; cc < 64; cc += 2)
                xsm[cc * LDX + nl] = lat_base[(size_t)(d0 + cc) * HW + nl];
            #pragma unroll
            for (int i = 0; i < 8; ++i) {
                int f4 = tid + 256 * i;
                int kk = f4 >> 4;
                int dq = f4 & 15;
                float4 v = *(const float4*)(cbk + (size_t)(k0 + kk) * DIMS + d0 + dq * 4);
                csm[(dq * 4 + 0) * LDX + kk] = v.x;
                csm[(dq * 4 + 1) * LDX + kk] = v.y;
                csm[(dq * 4 + 2) * LDX + kk] = v.z;
                csm[(dq * 4 + 3) * LDX + kk] = v.w;
            }
            __syncthreads();
            for (int d = 0; d < 64; ++d) {
                const float* xr = &xsm[d * LDX + mt * 8];
                const float* cr = &csm[d * LDX + kt * 8];
                float x8[8], c8[8];
                *(float4*)&x8[0] = *(const float4*)&xr[0];
                *(float4*)&x8[4] = *(const float4*)&xr[4];
                *(float4*)&c8[0] = *(const float4*)&cr[0];
                *(float4*)&c8[4] = *(const float4*)&cr[4];
                #pragma unroll
                for (int i = 0; i < 8; ++i)
                    #pragma unroll
                    for (int j = 0; j < 8; ++j)
                        acc[i][j] = fmaf(x8[i], c8[j], acc[i][j]);
            }
        }
        float cc2[8];
        #pragma unroll
        for (int j = 0; j < 8; ++j) cc2[j] = c2[k0 + kt * 8 + j];
        #pragma unroll
        for (int i = 0; i < 8; ++i)
            #pragma unroll
            for (int j = 0; j < 8; ++j) {
                float t = inv[i] * acc[i][j];
                float dist = fmaf(-2.f, t, cc2[j]);
                int kidx = k0 + kt * 8 + j;
                if (dist < best[i]) { best[i] = dist; bidx[i] = kidx; }
            }
    }
    if (tid < 128) red[tid] = ~0ull;
    __syncthreads();
    #pragma unroll
    for (int i = 0; i < 8; ++i) {
        unsigned long long p =
            ((unsigned long long)__float_as_uint(best[i]) << 32) | (unsigned)bidx[i];
        atomicMin(&red[mt * 8 + i], p);
    }
    __syncthreads();
    if (tid < 128) {
        int k = (int)(red[tid] & 0xFFFFFFFFu);
        idx_out[n0 + tid] = k;
        idxf_out[n0 + tid] = (float)k;
    }
}

__global__ __launch_bounds__(256) void k_gather(const float* __restrict__ cbk,
                                                const int* __restrict__ idx,
                                                float* __restrict__ out) {
    __shared__ float q[64 * 193];
    __shared__ int sidx[64];
    const int tid = threadIdx.x;
    const int n0 = blockIdx.x * 64;
    const int b = n0 >> 12;
    const int hw0 = n0 & 4095;
    const int lane = tid & 63;
    const int grp = tid >> 6;

    if (tid < 64) sidx[tid] = idx[n0 + tid];
    __syncthreads();
    for (int r = grp; r < 64; r += 4) {
        const float* row = cbk + (size_t)sidx[r] * DIMS;
        for (int c = lane; c < DIMS; c += 64) q[r * 193 + c] = row[c];
    }
    __syncthreads();
    float* obase = out + (size_t)b * DIMS * HW + hw0;
    for (int c = grp; c < DIMS; c += 4) {
        obase[(size_t)c * HW + lane] = q[lane * 193 + c];
    }
}

// ================================ launch ================================
extern "C" void kernel_launch(void* const* d_in, const int* in_sizes, int n_in,
                              void* d_out, int out_size, void* d_ws, size_t ws_size,
                              hipStream_t stream) {
    const float* latent = (const float*)d_in[0];
    const float* cbk = (const float*)d_in[1];
    float* out = (float*)d_out;
    float* out_q = out;
    float* out_idx = out + QELEMS;

    if (ws_size >= 2u * 1024u * 1024u) {
        // ws layout (bytes):
        char* w = (char*)d_ws;
        _Float16* Bpf = (_Float16*)w;                          //    393,216
        float* cbkT = (float*)(w + 393216);                    //    786,432
        float* c2 = (float*)(w + 1179648);                     //      4,096
        int* list = (int*)(w + 1183744);                       //    262,144
        int* cnt = (int*)(w + 1445888);                        //          4

        hipMemsetAsync(cnt, 0, 4, stream);
        k_prep_cb16<<<768, 256, 0, stream>>>(cbk, Bpf);
        k_c2<<<4, 256, 0, stream>>>(cbk, c2);
        k_cbT<<<KCB / 64, 256, 0, stream>>>(cbk, cbkT);
        k_gemm_f<<<512, 256, 0, stream>>>(latent, Bpf, cbk, out_q, out_idx,
                                          list, cnt);
        k_rescore16<<<512, 256, 0, stream>>>(latent, cbkT, cbk, c2, list, cnt,
                                             out_q, out_idx);
    } else {
        float* inv_norm = (float*)d_ws;
        float* c2 = inv_norm + NPTS;
        int* idx = (int*)(c2 + KCB);
        k_norms_fb<<<NPTS / 128, 256, 0, stream>>>(latent, inv_norm);
        k_c2<<<4, 256, 0, stream>>>(cbk, c2);
        k_dist_fb<<<NPTS / 128, 256, 0, stream>>>(latent, cbk, inv_norm, c2, idx, out_idx);
        k_gather<<<NPTS / 64, 256, 0, stream>>>(cbk, idx, out_q);
    }
}